// Round 3
// baseline (581.219 us; speedup 1.0000x reference)
//
#include <hip/hip_runtime.h>
#include <hip/hip_bf16.h>

typedef short bf16x8 __attribute__((ext_vector_type(8)));
typedef float f32x4  __attribute__((ext_vector_type(4)));

__device__ __forceinline__ unsigned short f2bf(float f) {
  unsigned int u = __float_as_uint(f);
  u += 0x7fffu + ((u >> 16) & 1u);   // round-to-nearest-even
  return (unsigned short)(u >> 16);
}

__device__ __forceinline__ f32x4 fzero() { f32x4 z = {0.f, 0.f, 0.f, 0.f}; return z; }

#define WQKV_FRAGS (6*36*64)          /* 13824 fragment-rows */
#define WP_FRAGS   (6*12*64)          /* 4608  fragment-rows */
#define WQKV_ELEMS (WQKV_FRAGS*8)     /* 110592 bf16 elems   */

// ---------------------------------------------------------------------------
// Prepack weights fp32 -> bf16 in MFMA B-fragment order.
// B-frag for tile (kt,nt): lane l holds B[kt*32+(l>>4)*8+j][nt*16+(l&15)], j=0..7
// Layout: frags[(kt*NT + nt)*64 + lane][8]  (16B per lane, coalesced)
// K-columns (192..383) get the 24^-0.5 scale baked in.
// ---------------------------------------------------------------------------
__global__ void prepack_weights(const float* __restrict__ wqkv,
                                const float* __restrict__ wproj,
                                unsigned short* __restrict__ ws) {
  int t = blockIdx.x * 256 + threadIdx.x;
  const float scale = 0.20412414523193154f;  // (192/8)^-0.5
  if (t < WQKV_FRAGS) {
    int kt  = t / (36*64);
    int rem = t - kt*(36*64);
    int nt  = rem >> 6;
    int l   = rem & 63;
    int n   = nt*16 + (l & 15);
    int k0  = kt*32 + (l >> 4)*8;
    float s = (n >= 192 && n < 384) ? scale : 1.0f;
    union { unsigned short us[8]; uint4 v; } u;
#pragma unroll
    for (int j = 0; j < 8; ++j) u.us[j] = f2bf(wqkv[(k0 + j)*576 + n] * s);
    *(uint4*)(ws + (size_t)t * 8) = u.v;
  } else if (t < WQKV_FRAGS + WP_FRAGS) {
    int t2  = t - WQKV_FRAGS;
    int kt  = t2 / (12*64);
    int rem = t2 - kt*(12*64);
    int nt  = rem >> 6;
    int l   = rem & 63;
    int n   = nt*16 + (l & 15);
    int k0  = kt*32 + (l >> 4)*8;
    union { unsigned short us[8]; uint4 v; } u;
#pragma unroll
    for (int j = 0; j < 8; ++j) u.us[j] = f2bf(wproj[(k0 + j)*192 + n]);
    *(uint4*)(ws + (size_t)WQKV_ELEMS + (size_t)t2 * 8) = u.v;
  }
}

// ---------------------------------------------------------------------------
// Fully-fused per-window kernel. 1 block = 1 window (64 tokens x 192 ch).
// 768 threads = 12 waves (3 waves/SIMD). bf16 MFMA 16x16x32, fp32 softmax.
// This round: softmax LDS access interleaved stride-8 (was 24-consecutive,
// an 8-way bank conflict = ~18% of block time per SQ_LDS_BANK_CONFLICT).
// ---------------------------------------------------------------------------
__launch_bounds__(768, 3)
__global__ void win_attn_fused(const float* __restrict__ x,
                               const unsigned short* __restrict__ wqkv_sw,
                               const unsigned short* __restrict__ wp_sw,
                               const float* __restrict__ bias,
                               float* __restrict__ out) {
  // LDS carve (153 KB). Padded strides keep 16B alignment + <=2-way banks.
  __shared__ __align__(16) unsigned char smem[156672];
  unsigned short* sX    = (unsigned short*)(smem);           // 64 x 200 bf16 (X, row-major)
  unsigned short* sQ    = (unsigned short*)(smem + 25600);   // 64 x 200 bf16 [n][d]
  unsigned short* sKt   = (unsigned short*)(smem + 51200);   // 192 x 72 bf16 [c][n]  (pre-scaled K^T)
  unsigned short* sVt   = (unsigned short*)(smem + 78848);   // 192 x 72 bf16 [d][n]  (V^T)
  float*          sAttn = (float*)(smem + 106496);           // 64 x 196 f32 [cc][d]
  unsigned short* sOut  = (unsigned short*)(smem);           // 64 x 72 bf16 [n][cc]  (aliases dead sX)

  const int tid  = threadIdx.x;
  const int lane = tid & 63;
  const int wv   = tid >> 6;      // wave 0..11
  const int l16  = lane & 15;
  const int lq   = lane >> 4;     // 0..3

  // ---- Phase 0: stage X (window is 12288 contiguous floats) -> bf16 LDS ----
  {
    const float4* xg = (const float4*)(x + (size_t)blockIdx.x * 12288);
#pragma unroll
    for (int i = 0; i < 4; ++i) {
      int idx = tid + i * 768;          // 0..3071
      float4 v = xg[idx];
      int e = idx << 2;
      unsigned short* p = sX + (e / 192) * 200 + (e % 192);
      p[0] = f2bf(v.x); p[1] = f2bf(v.y); p[2] = f2bf(v.z); p[3] = f2bf(v.w);
    }
  }
  __syncthreads();

  // ---- G1: QKV = X @ Wqkv  (M=64, N=576, K=192), 36 nt over 12 waves = 3 each ----
  {
    bf16x8 af[4][6];                    // A-frags: 4 m-strips x 6 k-tiles
#pragma unroll
    for (int ms = 0; ms < 4; ++ms)
#pragma unroll
      for (int kt = 0; kt < 6; ++kt)
        af[ms][kt] = *(const bf16x8*)(sX + (ms*16 + l16)*200 + kt*32 + lq*8);

    for (int nt = wv; nt < 36; nt += 12) {
      f32x4 acc[4] = {fzero(), fzero(), fzero(), fzero()};
      const bf16x8* bp = (const bf16x8*)wqkv_sw + nt*64 + lane;
#pragma unroll
      for (int kt = 0; kt < 6; ++kt) {
        bf16x8 b = bp[kt * (36*64)];
#pragma unroll
        for (int ms = 0; ms < 4; ++ms)
          acc[ms] = __builtin_amdgcn_mfma_f32_16x16x32_bf16(af[ms][kt], b, acc[ms], 0, 0, 0);
      }
      int c = nt*16 + l16;              // qkv column (wave-uniform category per nt)
#pragma unroll
      for (int ms = 0; ms < 4; ++ms) {
        int rb = ms*16 + lq*4;          // token row base
        if (c < 192) {                  // Q: row-major [n][d]
#pragma unroll
          for (int r = 0; r < 4; ++r) sQ[(rb + r)*200 + c] = f2bf(acc[ms][r]);
        } else if (c < 384) {           // K^T: [c][n] (contiguous n per lane)
#pragma unroll
          for (int r = 0; r < 4; ++r) sKt[(c - 192)*72 + rb + r] = f2bf(acc[ms][r]);
        } else {                        // V^T: [d][n]
#pragma unroll
          for (int r = 0; r < 4; ++r) sVt[(c - 384)*72 + rb + r] = f2bf(acc[ms][r]);
        }
      }
    }
  }
  __syncthreads();

  f32x4 accF[4];                        // persistent proj accumulators (nt = wv)
#pragma unroll
  for (int m = 0; m < 4; ++m) accF[m] = fzero();

  for (int cb = 0; cb < 3; ++cb) {      // attn-row blocks of 64
    // ---- G2: logits[cc][d] = sum_n K^T[c][n] * V[n][d]  (M=64,N=192,K=64) ----
    // 12 dt-tiles over 12 waves = exactly 1 each.
    {
      bf16x8 ak[4][2];
#pragma unroll
      for (int ms = 0; ms < 4; ++ms)
#pragma unroll
        for (int kt = 0; kt < 2; ++kt)
          ak[ms][kt] = *(const bf16x8*)(sKt + (cb*64 + ms*16 + l16)*72 + kt*32 + lq*8);
      int dt = wv;                      // 0..11
      f32x4 acc[4] = {fzero(), fzero(), fzero(), fzero()};
#pragma unroll
      for (int kt = 0; kt < 2; ++kt) {
        bf16x8 b = *(const bf16x8*)(sVt + (dt*16 + l16)*72 + kt*32 + lq*8);
#pragma unroll
        for (int ms = 0; ms < 4; ++ms)
          acc[ms] = __builtin_amdgcn_mfma_f32_16x16x32_bf16(ak[ms][kt], b, acc[ms], 0, 0, 0);
      }
      int d = dt*16 + l16;
#pragma unroll
      for (int ms = 0; ms < 4; ++ms)
#pragma unroll
        for (int r = 0; r < 4; ++r)
          sAttn[(ms*16 + lq*4 + r)*196 + d] = acc[ms][r];
    }
    __syncthreads();

    // ---- softmax over d (fp32, 8 threads/row, STRIDE-8 interleave) ----
    // bank = (4*row + seg + 8*i) mod 32 -> <=2 lanes/bank (conflict-free);
    // the old seg*24-consecutive mapping was an 8-way conflict.
    if (tid < 512) {
      int row = tid >> 3, seg = tid & 7;
      float* rp = sAttn + row*196 + seg;
      float v0[24];
      float mx = -3.0e38f;
#pragma unroll
      for (int i = 0; i < 24; ++i) { v0[i] = rp[i*8]; mx = fmaxf(mx, v0[i]); }
      mx = fmaxf(mx, __shfl_xor(mx, 1));
      mx = fmaxf(mx, __shfl_xor(mx, 2));
      mx = fmaxf(mx, __shfl_xor(mx, 4));
      float s = 0.f;
#pragma unroll
      for (int i = 0; i < 24; ++i) { float e = __expf(v0[i] - mx); v0[i] = e; s += e; }
      s += __shfl_xor(s, 1);
      s += __shfl_xor(s, 2);
      s += __shfl_xor(s, 4);
      float inv = 1.0f / s;
#pragma unroll
      for (int i = 0; i < 24; ++i) rp[i*8] = v0[i] * inv;
    }
    __syncthreads();

    // ---- G3: out[:,cc] = Q @ attn_blk^T  (M=64, N=64, K=192), 8 waves ----
    if (wv < 8) {
      int ct = wv & 3, mh = wv >> 2;    // wave: 1 col-tile x 2 m-strips
      bf16x8 aq[2][6];
#pragma unroll
      for (int mi = 0; mi < 2; ++mi)
#pragma unroll
        for (int kt = 0; kt < 6; ++kt)
          aq[mi][kt] = *(const bf16x8*)(sQ + ((mh*2 + mi)*16 + l16)*200 + kt*32 + lq*8);
      f32x4 acc[2] = {fzero(), fzero()};
#pragma unroll
      for (int kt = 0; kt < 6; ++kt) {
        // B[k=d][n=cc] = attn[cc][d]: 8 consecutive d per lane, cvt fp32->bf16
        const float* ap = sAttn + (ct*16 + l16)*196 + kt*32 + lq*8;
        float4 f0 = *(const float4*)ap;
        float4 f1 = *(const float4*)(ap + 4);
        bf16x8 b;
        b[0] = (short)f2bf(f0.x); b[1] = (short)f2bf(f0.y);
        b[2] = (short)f2bf(f0.z); b[3] = (short)f2bf(f0.w);
        b[4] = (short)f2bf(f1.x); b[5] = (short)f2bf(f1.y);
        b[6] = (short)f2bf(f1.z); b[7] = (short)f2bf(f1.w);
#pragma unroll
        for (int mi = 0; mi < 2; ++mi)
          acc[mi] = __builtin_amdgcn_mfma_f32_16x16x32_bf16(aq[mi][kt], b, acc[mi], 0, 0, 0);
      }
#pragma unroll
      for (int mi = 0; mi < 2; ++mi)
#pragma unroll
        for (int r = 0; r < 4; ++r)
          sOut[((mh*2 + mi)*16 + lq*4 + r)*72 + ct*16 + l16] = f2bf(acc[mi][r]);
    }
    __syncthreads();

    // ---- G4: accF += out_blk @ Wp[cb*64 : +64, :]  (nt = wv, 12 waves) ----
    {
      bf16x8 ao[4][2];
#pragma unroll
      for (int ms = 0; ms < 4; ++ms)
#pragma unroll
        for (int kt = 0; kt < 2; ++kt)
          ao[ms][kt] = *(const bf16x8*)(sOut + (ms*16 + l16)*72 + kt*32 + lq*8);
      const bf16x8* bp = (const bf16x8*)wp_sw + ((cb*2)*12 + wv)*64 + lane;
#pragma unroll
      for (int kt = 0; kt < 2; ++kt) {
        bf16x8 b = bp[kt * (12*64)];
#pragma unroll
        for (int ms = 0; ms < 4; ++ms)
          accF[ms] = __builtin_amdgcn_mfma_f32_16x16x32_bf16(ao[ms][kt], b, accF[ms], 0, 0, 0);
      }
    }
    // no barrier needed: next G2 writes sAttn (last read pre-G4-barrier);
    // next writer of sOut (G3) is behind two barriers.
  }

  // ---- epilogue: += bias, fp32 store (nt = wv covers all 12 col-tiles) ----
  {
    int e = wv*16 + l16;
    float bv = bias[e];
    float* op = out + (size_t)blockIdx.x * 12288;
#pragma unroll
    for (int ms = 0; ms < 4; ++ms)
#pragma unroll
      for (int r = 0; r < 4; ++r)
        op[(ms*16 + lq*4 + r)*192 + e] = accF[ms][r] + bv;
  }
}

extern "C" void kernel_launch(void* const* d_in, const int* in_sizes, int n_in,
                              void* d_out, int out_size, void* d_ws, size_t ws_size,
                              hipStream_t stream) {
  const float* x     = (const float*)d_in[0];
  const float* wqkv  = (const float*)d_in[1];
  const float* wproj = (const float*)d_in[2];
  const float* bproj = (const float*)d_in[3];
  unsigned short* ws = (unsigned short*)d_ws;

  int nwin = in_sizes[0] / 12288;      // B * L / 64 windows (4608)

  prepack_weights<<<72, 256, 0, stream>>>(wqkv, wproj, ws);
  win_attn_fused<<<nwin, 768, 0, stream>>>(x, ws, ws + WQKV_ELEMS, bproj, (float*)d_out);
}

// Round 5
// 518.401 us; speedup vs baseline: 1.1212x; 1.1212x over previous
//
#include <hip/hip_runtime.h>
#include <hip/hip_bf16.h>

typedef short bf16x8 __attribute__((ext_vector_type(8)));
typedef float f32x4  __attribute__((ext_vector_type(4)));

__device__ __forceinline__ unsigned short f2bf(float f) {
  unsigned int u = __float_as_uint(f);
  u += 0x7fffu + ((u >> 16) & 1u);   // round-to-nearest-even
  return (unsigned short)(u >> 16);
}

__device__ __forceinline__ f32x4 fzero() { f32x4 z = {0.f, 0.f, 0.f, 0.f}; return z; }

#define WQKV_FRAGS (6*36*64)          /* 13824 fragment-rows */
#define WP_FRAGS   (6*12*64)          /* 4608  fragment-rows */
#define WQKV_ELEMS (WQKV_FRAGS*8)     /* 110592 bf16 elems   */

// ---------------------------------------------------------------------------
// Prepack weights fp32 -> bf16 in MFMA B-fragment order.
// B-frag for tile (kt,nt): lane l holds B[kt*32+(l>>4)*8+j][nt*16+(l&15)], j=0..7
// K-columns (192..383) get the 24^-0.5 scale baked in.
// ---------------------------------------------------------------------------
__global__ void prepack_weights(const float* __restrict__ wqkv,
                                const float* __restrict__ wproj,
                                unsigned short* __restrict__ ws) {
  int t = blockIdx.x * 256 + threadIdx.x;
  const float scale = 0.20412414523193154f;  // (192/8)^-0.5
  if (t < WQKV_FRAGS) {
    int kt  = t / (36*64);
    int rem = t - kt*(36*64);
    int nt  = rem >> 6;
    int l   = rem & 63;
    int n   = nt*16 + (l & 15);
    int k0  = kt*32 + (l >> 4)*8;
    float s = (n >= 192 && n < 384) ? scale : 1.0f;
    union { unsigned short us[8]; uint4 v; } u;
#pragma unroll
    for (int j = 0; j < 8; ++j) u.us[j] = f2bf(wqkv[(k0 + j)*576 + n] * s);
    *(uint4*)(ws + (size_t)t * 8) = u.v;
  } else if (t < WQKV_FRAGS + WP_FRAGS) {
    int t2  = t - WQKV_FRAGS;
    int kt  = t2 / (12*64);
    int rem = t2 - kt*(12*64);
    int nt  = rem >> 6;
    int l   = rem & 63;
    int n   = nt*16 + (l & 15);
    int k0  = kt*32 + (l >> 4)*8;
    union { unsigned short us[8]; uint4 v; } u;
#pragma unroll
    for (int j = 0; j < 8; ++j) u.us[j] = f2bf(wproj[(k0 + j)*192 + n]);
    *(uint4*)(ws + (size_t)WQKV_ELEMS + (size_t)t2 * 8) = u.v;
  }
}

// ---------------------------------------------------------------------------
// Fully-fused per-window kernel. 1 block = 1 window (64 tokens x 192 ch).
// 768 threads = 12 waves. Transposed G2' (logits^T via A=V^T, B=K^T) ->
// each lane owns 16 logits of ONE attn row -> register softmax; P stored
// once as bf16 (aliases dead sX); G3 reads P directly as B-frags.
// sAttn (50KB f32) eliminated; LDS 156.7K -> 117.2K.
// ---------------------------------------------------------------------------
__launch_bounds__(768, 3)
__global__ void win_attn_fused(const float* __restrict__ x,
                               const unsigned short* __restrict__ wqkv_sw,
                               const unsigned short* __restrict__ wp_sw,
                               const float* __restrict__ bias,
                               float* __restrict__ out) {
  __shared__ __align__(16) unsigned char smem[117248];
  unsigned short* sX   = (unsigned short*)(smem);           // 64 x 200 bf16 (X staging)
  unsigned short* sP   = (unsigned short*)(smem);           // 64 x 200 bf16 probs [cc][d] (aliases dead sX)
  unsigned short* sQ   = (unsigned short*)(smem + 25600);   // 64 x 200 bf16 [tok][d]
  unsigned short* sKt  = (unsigned short*)(smem + 51200);   // 192 x 72 bf16 [c][tok] (pre-scaled)
  unsigned short* sVt  = (unsigned short*)(smem + 78848);   // 192 x 72 bf16 [d][tok]
  unsigned short* sOut = (unsigned short*)(smem + 106496);  // 64 x 72 bf16 [tok][cc]
  float2*         sRed = (float2*)(smem + 115712);          // 3 x 64 (max,sum)

  const int tid  = threadIdx.x;
  const int lane = tid & 63;
  const int wv   = tid >> 6;      // wave 0..11
  const int l16  = lane & 15;
  const int lq   = lane >> 4;     // 0..3

  // ---- Phase 0: stage X (window is 12288 contiguous floats) -> bf16 LDS ----
  {
    const float4* xg = (const float4*)(x + (size_t)blockIdx.x * 12288);
#pragma unroll
    for (int i = 0; i < 4; ++i) {
      int idx = tid + i * 768;          // 0..3071
      float4 v = xg[idx];
      int e = idx << 2;
      unsigned short* p = sX + (e / 192) * 200 + (e % 192);
      p[0] = f2bf(v.x); p[1] = f2bf(v.y); p[2] = f2bf(v.z); p[3] = f2bf(v.w);
    }
  }
  __syncthreads();

  // ---- G1: QKV = X @ Wqkv  (M=64, N=576, K=192), 36 nt over 12 waves ----
  {
    bf16x8 af[4][6];                    // A-frags: 4 m-strips x 6 k-tiles
#pragma unroll
    for (int ms = 0; ms < 4; ++ms)
#pragma unroll
      for (int kt = 0; kt < 6; ++kt)
        af[ms][kt] = *(const bf16x8*)(sX + (ms*16 + l16)*200 + kt*32 + lq*8);

    for (int nt = wv; nt < 36; nt += 12) {
      f32x4 acc[4] = {fzero(), fzero(), fzero(), fzero()};
      const bf16x8* bp = (const bf16x8*)wqkv_sw + nt*64 + lane;
#pragma unroll
      for (int kt = 0; kt < 6; ++kt) {
        bf16x8 b = bp[kt * (36*64)];
#pragma unroll
        for (int ms = 0; ms < 4; ++ms)
          acc[ms] = __builtin_amdgcn_mfma_f32_16x16x32_bf16(af[ms][kt], b, acc[ms], 0, 0, 0);
      }
      int c = nt*16 + l16;              // qkv column (wave-uniform category per nt)
#pragma unroll
      for (int ms = 0; ms < 4; ++ms) {
        int rb = ms*16 + lq*4;          // token row base
        if (c < 192) {                  // Q: row-major [tok][d]
#pragma unroll
          for (int r = 0; r < 4; ++r) sQ[(rb + r)*200 + c] = f2bf(acc[ms][r]);
        } else if (c < 384) {           // K^T: [c][tok] (contiguous tok per lane)
#pragma unroll
          for (int r = 0; r < 4; ++r) sKt[(c - 192)*72 + rb + r] = f2bf(acc[ms][r]);
        } else {                        // V^T: [d][tok]
#pragma unroll
          for (int r = 0; r < 4; ++r) sVt[(c - 384)*72 + rb + r] = f2bf(acc[ms][r]);
        }
      }
    }
  }
  __syncthreads();

  f32x4 accF[4];                        // persistent proj accumulators (nt = wv)
#pragma unroll
  for (int m = 0; m < 4; ++m) accF[m] = fzero();

  const int ccs = wv & 3;               // cc strip (16 rows) within 64-row chunk
  const int thr = wv >> 2;              // d-third 0..2 (64 d values each)

  // cb-invariant A-frags: V^T rows for this wave's d-third
  bf16x8 av[4][2];
#pragma unroll
  for (int mi = 0; mi < 4; ++mi)
#pragma unroll
    for (int kt = 0; kt < 2; ++kt) {
      int rd = thr*64 + mi*16 + l16;
      av[mi][kt] = *(const bf16x8*)(sVt + rd*72 + kt*32 + lq*8);
    }

  // cb-invariant Q A-frags for G3 (first 8 waves)
  const int ct = wv & 3, mh = wv >> 2;  // G3 split: col-tile x 2 m-strips
  bf16x8 aq[2][6];
  if (wv < 8) {
#pragma unroll
    for (int mi = 0; mi < 2; ++mi)
#pragma unroll
      for (int kt = 0; kt < 6; ++kt)
        aq[mi][kt] = *(const bf16x8*)(sQ + ((mh*2 + mi)*16 + l16)*200 + kt*32 + lq*8);
  }

  for (int cb = 0; cb < 3; ++cb) {      // attn-row chunks of 64
    // ---- G2': logits^T[d][cc] = sum_tok V^T[d][tok] * K^T[cc][tok] ----
    // D[row=d (lq*4+r within tile)][col=cc (l16)] -> lane holds 16 logits of
    // one attn row cc = cb*64 + ccs*16 + l16, at d = thr*64 + mi*16 + lq*4 + r.
    f32x4 lac[4] = {fzero(), fzero(), fzero(), fzero()};
    {
      int rc = cb*64 + ccs*16 + l16;    // K^T row = this lane's attn row
#pragma unroll
      for (int kt = 0; kt < 2; ++kt) {
        bf16x8 b = *(const bf16x8*)(sKt + rc*72 + kt*32 + lq*8);
#pragma unroll
        for (int mi = 0; mi < 4; ++mi)
          lac[mi] = __builtin_amdgcn_mfma_f32_16x16x32_bf16(av[mi][kt], b, lac[mi], 0, 0, 0);
      }
    }

    // ---- softmax: in-register + shfl (combine lq) + cross-third exchange ----
    int ccl = ccs*16 + l16;             // chunk-local attn row 0..63
    {
      float l[16];
#pragma unroll
      for (int mi = 0; mi < 4; ++mi)
#pragma unroll
        for (int r = 0; r < 4; ++r) l[mi*4+r] = lac[mi][r];
      float mx = l[0];
#pragma unroll
      for (int i = 1; i < 16; ++i) mx = fmaxf(mx, l[i]);
      mx = fmaxf(mx, __shfl_xor(mx, 16));
      mx = fmaxf(mx, __shfl_xor(mx, 32));
      float s = 0.f;
#pragma unroll
      for (int i = 0; i < 16; ++i) { float e = __expf(l[i] - mx); l[i] = e; s += e; }
      s += __shfl_xor(s, 16);
      s += __shfl_xor(s, 32);
      if (lane < 16) sRed[thr*64 + ccl] = make_float2(mx, s);
      __syncthreads();                  // bar1
      float2 r0 = sRed[ccl], r1 = sRed[64 + ccl], r2 = sRed[128 + ccl];
      float M = fmaxf(fmaxf(r0.x, r1.x), r2.x);
      float S = r0.y*__expf(r0.x - M) + r1.y*__expf(r1.x - M) + r2.y*__expf(r2.x - M);
      float sc = __expf(mx - M) / S;
      // write P (bf16) once: rows ccl, cols d0..d0+3 per mi
#pragma unroll
      for (int mi = 0; mi < 4; ++mi) {
        int d0 = thr*64 + mi*16 + lq*4;
        union { unsigned short us[4]; uint2 v; } u;
        u.us[0] = f2bf(l[mi*4+0]*sc); u.us[1] = f2bf(l[mi*4+1]*sc);
        u.us[2] = f2bf(l[mi*4+2]*sc); u.us[3] = f2bf(l[mi*4+3]*sc);
        *(uint2*)(sP + ccl*200 + d0) = u.v;
      }
    }
    __syncthreads();                    // bar2

    // ---- G3: out_blk[tok][cc] = Q @ P^T  (M=64, N=64, K=192), 8 waves ----
    if (wv < 8) {
      f32x4 acc[2] = {fzero(), fzero()};
#pragma unroll
      for (int kt = 0; kt < 6; ++kt) {
        // B[k=d][n=cc]: lane needs P[ct*16+l16][kt*32+lq*8 ..+7] -> direct b128
        bf16x8 b = *(const bf16x8*)(sP + (ct*16 + l16)*200 + kt*32 + lq*8);
#pragma unroll
        for (int mi = 0; mi < 2; ++mi)
          acc[mi] = __builtin_amdgcn_mfma_f32_16x16x32_bf16(aq[mi][kt], b, acc[mi], 0, 0, 0);
      }
#pragma unroll
      for (int mi = 0; mi < 2; ++mi)
#pragma unroll
        for (int r = 0; r < 4; ++r)
          sOut[((mh*2 + mi)*16 + lq*4 + r)*72 + ct*16 + l16] = f2bf(acc[mi][r]);
    }
    __syncthreads();                    // bar3

    // ---- G4: accF += out_blk @ Wp[cb*64 : +64, :]  (nt = wv, 12 waves) ----
    {
      bf16x8 ao[4][2];
#pragma unroll
      for (int ms = 0; ms < 4; ++ms)
#pragma unroll
        for (int kt = 0; kt < 2; ++kt)
          ao[ms][kt] = *(const bf16x8*)(sOut + (ms*16 + l16)*72 + kt*32 + lq*8);
      const bf16x8* bp = (const bf16x8*)wp_sw + ((cb*2)*12 + wv)*64 + lane;
#pragma unroll
      for (int kt = 0; kt < 2; ++kt) {
        bf16x8 b = bp[kt * (12*64)];
#pragma unroll
        for (int ms = 0; ms < 4; ++ms)
          accF[ms] = __builtin_amdgcn_mfma_f32_16x16x32_bf16(ao[ms][kt], b, accF[ms], 0, 0, 0);
      }
    }
    // no barrier: G2'(cb+1) is register-only; first LDS write after G4 is the
    // sRed write, whose previous readers are all behind bar2(cb).
  }

  // ---- epilogue: += bias, fp32 store (nt = wv covers all 12 col-tiles) ----
  {
    int e = wv*16 + l16;
    float bv = bias[e];
    float* op = out + (size_t)blockIdx.x * 12288;
#pragma unroll
    for (int ms = 0; ms < 4; ++ms)
#pragma unroll
      for (int r = 0; r < 4; ++r)
        op[(ms*16 + lq*4 + r)*192 + e] = accF[ms][r] + bv;
  }
}

extern "C" void kernel_launch(void* const* d_in, const int* in_sizes, int n_in,
                              void* d_out, int out_size, void* d_ws, size_t ws_size,
                              hipStream_t stream) {
  const float* x     = (const float*)d_in[0];
  const float* wqkv  = (const float*)d_in[1];
  const float* wproj = (const float*)d_in[2];
  const float* bproj = (const float*)d_in[3];
  unsigned short* ws = (unsigned short*)d_ws;

  int nwin = in_sizes[0] / 12288;      // B * L / 64 windows (4608)

  prepack_weights<<<72, 256, 0, stream>>>(wqkv, wproj, ws);
  win_attn_fused<<<nwin, 768, 0, stream>>>(x, ws, ws + WQKV_ELEMS, bproj, (float*)d_out);
}